// Round 1
// baseline (149.992 us; speedup 1.0000x reference)
//
#include <hip/hip_runtime.h>
#include <hip/hip_bf16.h>

#define HEADS 4
#define ODIM 64
#define HD 256          // HEADS*ODIM
#define NEG_SLOPE 0.2f
#define SPLITS 4
#define BJ 128          // j-chunk

typedef __attribute__((ext_vector_type(8))) short bf16x8;
typedef __attribute__((ext_vector_type(4))) float floatx4;
typedef __attribute__((ext_vector_type(2))) float floatx2;

// ============ pack x and W -> bf16 hi/lo MFMA fragments (one launch) ============
// A-frag layout: frag[(mc*Kc + kc)][lane][8], lane=(l16,q): A[m=mc*16+l16][k=kc*32+q*8+p]
// B-frag layout: frag[(nc*Kc + kc)][lane][8], lane=(l16,q): B[k=kc*32+q*8+p][n=nc*16+l16]
__global__ __launch_bounds__(256) void pack_xw(const float* __restrict__ x,
                                               const float* __restrict__ W,
                                               __hip_bfloat16* __restrict__ xh,
                                               __hip_bfloat16* __restrict__ xl,
                                               __hip_bfloat16* __restrict__ wh,
                                               __hip_bfloat16* __restrict__ wl,
                                               int K, int nxb) {
    const int b = blockIdx.x;
    const int Kc = K >> 5;
    if (b < nxb) {
        const int g = b * 256 + threadIdx.x;
        const int lane = g & 63, frag = g >> 6;
        const int kc = frag % Kc, mc = frag / Kc;
        const int l16 = lane & 15, q = lane >> 4;
        const float* src = x + (size_t)(mc * 16 + l16) * K + kc * 32 + q * 8;
        const float4 v0 = *(const float4*)src;
        const float4 v1 = *(const float4*)(src + 4);
        const float vv[8] = {v0.x, v0.y, v0.z, v0.w, v1.x, v1.y, v1.z, v1.w};
        union { __hip_bfloat16 b[8]; bf16x8 v; } H, L;
        #pragma unroll
        for (int p = 0; p < 8; ++p) {
            H.b[p] = __float2bfloat16(vv[p]);
            L.b[p] = __float2bfloat16(vv[p] - __bfloat162float(H.b[p]));
        }
        *(bf16x8*)&xh[(size_t)frag * 512 + lane * 8] = H.v;
        *(bf16x8*)&xl[(size_t)frag * 512 + lane * 8] = L.v;
    } else {
        const int g = (b - nxb) * 256 + threadIdx.x;
        const int lane = g & 63, frag = g >> 6;
        const int kc = frag % Kc, nc = frag / Kc;
        const int l16 = lane & 15, q = lane >> 4;
        union { __hip_bfloat16 b[8]; bf16x8 v; } H, L;
        #pragma unroll
        for (int p = 0; p < 8; ++p) {
            const float w = W[(size_t)(kc * 32 + q * 8 + p) * HD + nc * 16 + l16];
            H.b[p] = __float2bfloat16(w);
            L.b[p] = __float2bfloat16(w - __bfloat162float(H.b[p]));
        }
        *(bf16x8*)&wh[(size_t)frag * 512 + lane * 8] = H.v;
        *(bf16x8*)&wl[(size_t)frag * 512 + lane * 8] = L.v;
    }
}

// ============ fused GEMM: h = x@W (hi/lo bf16 MFMA) + E epilogue + B-frag pack of h ============
// block = 128 thr (2 waves, 16 rows each), grid (n/32, HEADS) = 512 blocks (2/CU).
__global__ __launch_bounds__(128) void gemm_fused(
    const __hip_bfloat16* __restrict__ xh, const __hip_bfloat16* __restrict__ xl,
    const __hip_bfloat16* __restrict__ wh, const __hip_bfloat16* __restrict__ wl,
    const float* __restrict__ att, float4* __restrict__ E4,
    __hip_bfloat16* __restrict__ hbB, int n, int K) {

    __shared__ __hip_bfloat16 T[64][40];   // h^T tile [d][j(32)], stride 40 (16B-aligned rows)

    const int tid = threadIdx.x, wave = tid >> 6, lane = tid & 63;
    const int q = lane >> 4, l16 = lane & 15;
    const int m0 = blockIdx.x * 32;
    const int head = blockIdx.y;
    const int Kc = K >> 5;
    const int mc = (m0 >> 4) + wave;

    floatx4 acc[4] = {{0.f,0.f,0.f,0.f},{0.f,0.f,0.f,0.f},{0.f,0.f,0.f,0.f},{0.f,0.f,0.f,0.f}};

    const __hip_bfloat16* Axh = xh + (size_t)mc * Kc * 512 + lane * 8;
    const __hip_bfloat16* Axl = xl + (size_t)mc * Kc * 512 + lane * 8;
    const __hip_bfloat16* Bwh = wh + lane * 8;
    const __hip_bfloat16* Bwl = wl + lane * 8;
    #pragma unroll 2
    for (int kc = 0; kc < Kc; ++kc) {
        const bf16x8 ah = *(const bf16x8*)(Axh + (size_t)kc * 512);
        const bf16x8 al = *(const bf16x8*)(Axl + (size_t)kc * 512);
        bf16x8 bh[4], bl[4];
        #pragma unroll
        for (int nt = 0; nt < 4; ++nt) {
            const size_t fo = (size_t)((head * 4 + nt) * Kc + kc) * 512;
            bh[nt] = *(const bf16x8*)(Bwh + fo);
            bl[nt] = *(const bf16x8*)(Bwl + fo);
        }
        // pass-major order: dependency distance 4 between same-acc MFMAs
        #pragma unroll
        for (int nt = 0; nt < 4; ++nt)
            acc[nt] = __builtin_amdgcn_mfma_f32_16x16x32_bf16(ah, bh[nt], acc[nt], 0, 0, 0);
        #pragma unroll
        for (int nt = 0; nt < 4; ++nt)
            acc[nt] = __builtin_amdgcn_mfma_f32_16x16x32_bf16(ah, bl[nt], acc[nt], 0, 0, 0);
        #pragma unroll
        for (int nt = 0; nt < 4; ++nt)
            acc[nt] = __builtin_amdgcn_mfma_f32_16x16x32_bf16(al, bh[nt], acc[nt], 0, 0, 0);
    }

    // ---- E epilogue: e_src/e_dst row sums via shuffle over the 16-lane group ----
    float as_v[4], ad_v[4];
    #pragma unroll
    for (int nt = 0; nt < 4; ++nt) {
        as_v[nt] = att[head * 2 * ODIM + nt * 16 + l16];
        ad_v[nt] = att[head * 2 * ODIM + ODIM + nt * 16 + l16];
    }
    #pragma unroll
    for (int r = 0; r < 4; ++r) {
        float ps = 0.f, pd = 0.f;
        #pragma unroll
        for (int nt = 0; nt < 4; ++nt) {
            ps = fmaf(acc[nt][r], as_v[nt], ps);
            pd = fmaf(acc[nt][r], ad_v[nt], pd);
        }
        #pragma unroll
        for (int m = 1; m <= 8; m <<= 1) {
            ps += __shfl_xor(ps, m, 64);
            pd += __shfl_xor(pd, m, 64);
        }
        if (l16 == 0) {
            const int i = m0 + wave * 16 + q * 4 + r;
            E4[i * HEADS + head] = make_float4(__expf(ps), __expf(NEG_SLOPE * ps),
                                               __expf(pd), __expf(NEG_SLOPE * pd));
        }
    }

    // ---- write h tile transposed to LDS as bf16 ----
    #pragma unroll
    for (int nt = 0; nt < 4; ++nt) {
        union { __hip_bfloat16 b[4]; uint2 u; } pk;
        #pragma unroll
        for (int r = 0; r < 4; ++r) pk.b[r] = __float2bfloat16(acc[nt][r]);
        *(uint2*)&T[nt * 16 + l16][wave * 16 + q * 4] = pk.u;
    }
    __syncthreads();

    // ---- emit packed B-frags of h: frag[(head*(n/32) + j32)*4 + nt][lane][8] ----
    #pragma unroll
    for (int ffi = 0; ffi < 2; ++ffi) {
        const int f = wave + ffi * 2;   // nt
        const bf16x8 v = *(const bf16x8*)&T[f * 16 + l16][q * 8];
        const size_t frag = ((size_t)head * (n >> 5) + (m0 >> 5)) * 4 + f;
        *(bf16x8*)&hbB[frag * 512 + lane * 8] = v;
    }
}

// ============ aggregate: out_split[s][i][h*64+d] = sum_j P[i,j,h] h[j,h,d] ============
// block: 4 waves (wave=head), i-tile 16, j-chunk 128, K split 4-way.
// Grid (n/16, SPLITS) = 1024 blocks -> 4 blocks/CU (4 independent barrier groups/SIMD),
// double the previous 2/CU: attacks the latency-bound profile (all pipes <21% busy).
// Depth-2 adj/E register prefetch; per-ks B-frag software pipeline; dbuf LDS.
__global__ __launch_bounds__(256, 4) void aggregate(
    const int* __restrict__ adj, const float4* __restrict__ E4,
    const __hip_bfloat16* __restrict__ hbB, float* __restrict__ outsp,
    float* __restrict__ densp, int n, int KR) {

    __shared__ unsigned short adjL[2][16][136];  // masks; stride 136 ush = 68 dw (balanced b128 banks)
    __shared__ float2 EdL[2][HEADS][BJ];         // dst-side exps per chunk

    const int tid = threadIdx.x;
    const int wave = tid >> 6, lane = tid & 63;
    const int q = lane >> 4, l16 = lane & 15, q8 = (lane >> 4) * 8;
    const int i0 = blockIdx.x * 16;
    const int K0 = blockIdx.y * KR;

    // staging maps
    const int sr = tid >> 4, sg = (tid & 15) * 8;  // adj: 16 rows x 8-int groups
    const int je = tid >> 1, heb = (tid & 1) * 2;  // E: 128 j x 2 head-pairs

    // src-side exps for this lane's row (head = wave)
    floatx2 es12;
    {
        const float4 e = E4[(i0 + l16) * HEADS + wave];
        es12[0] = e.x; es12[1] = e.y;
    }

    // ones-column B-frag for MFMA-based denominator
    union { short s[8]; bf16x8 v; } bones;
    #pragma unroll
    for (int p = 0; p < 8; ++p) bones.s[p] = (l16 == 0) ? (short)0x3F80 : (short)0;

    floatx4 acc[4];
    floatx4 accd = (floatx4){0.f, 0.f, 0.f, 0.f};
    #pragma unroll
    for (int nt = 0; nt < 4; ++nt) acc[nt] = (floatx4){0.f, 0.f, 0.f, 0.f};

    const int* aprow = &adj[(size_t)(i0 + sr) * n];
    const size_t fragbase = (size_t)wave * (n >> 5) * 4;   // hbB frag base for this head

    int4 ajA[2], ajB[2];
    float4 evA0, evA1, evB0, evB1;

    auto loadPref = [&](int jc, int4* aj, float4& e0, float4& e1) {
        const int4* ap = (const int4*)(aprow + jc + sg);
        aj[0] = ap[0]; aj[1] = ap[1];
        e0 = E4[(jc + je) * HEADS + heb];
        e1 = E4[(jc + je) * HEADS + heb + 1];
    };
    auto stage = [&](int buf, const int4* aj, const float4& e0, const float4& e1) {
        const int* av = (const int*)aj;
        uint4 u;
        u.x = (av[0] > 0 ? 0xFFFFu : 0u) | (av[1] > 0 ? 0xFFFF0000u : 0u);
        u.y = (av[2] > 0 ? 0xFFFFu : 0u) | (av[3] > 0 ? 0xFFFF0000u : 0u);
        u.z = (av[4] > 0 ? 0xFFFFu : 0u) | (av[5] > 0 ? 0xFFFF0000u : 0u);
        u.w = (av[6] > 0 ? 0xFFFFu : 0u) | (av[7] > 0 ? 0xFFFF0000u : 0u);
        *(uint4*)&adjL[buf][sr][sg] = u;
        EdL[buf][heb][je]     = make_float2(e0.z, e0.w);
        EdL[buf][heb + 1][je] = make_float2(e1.z, e1.w);
    };

    auto computeChunk = [&](int buf, int jc) {
        bf16x8 bA[4], bB[4];
        #pragma unroll
        for (int nt = 0; nt < 4; ++nt)
            bA[nt] = *(const bf16x8*)&hbB[(fragbase + (size_t)(jc >> 5) * 4 + nt) * 512 + lane * 8];
        #pragma unroll
        for (int ks = 0; ks < 4; ++ks) {
            const bf16x8* bcur = (ks & 1) ? bB : bA;
            bf16x8* bnxt = (ks & 1) ? bA : bB;
            if (ks < 3) {   // prefetch next ks while computing this one
                #pragma unroll
                for (int nt = 0; nt < 4; ++nt)
                    bnxt[nt] = *(const bf16x8*)&hbB[(fragbase + (size_t)((jc >> 5) + ks + 1) * 4 + nt) * 512 + lane * 8];
            }
            const float4* ep = (const float4*)&EdL[buf][wave][ks * 32 + q8];
            const float4 e01 = ep[0], e23 = ep[1], e45 = ep[2], e67 = ep[3];
            floatx2 ed[8];
            ed[0][0]=e01.x; ed[0][1]=e01.y;  ed[1][0]=e01.z; ed[1][1]=e01.w;
            ed[2][0]=e23.x; ed[2][1]=e23.y;  ed[3][0]=e23.z; ed[3][1]=e23.w;
            ed[4][0]=e45.x; ed[4][1]=e45.y;  ed[5][0]=e45.z; ed[5][1]=e45.w;
            ed[6][0]=e67.x; ed[6][1]=e67.y;  ed[7][0]=e67.z; ed[7][1]=e67.w;
            const uint4 msk = *(const uint4*)&adjL[buf][l16][ks * 32 + q8];
            const unsigned int mm[4] = {msk.x, msk.y, msk.z, msk.w};
            union { unsigned int u[4]; bf16x8 v; } af;
            #pragma unroll
            for (int p = 0; p < 4; ++p) {
                const floatx2 pa = es12 * ed[2 * p];
                const floatx2 pb = es12 * ed[2 * p + 1];
                const float wa = fmaxf(pa[0], pa[1]);   // leaky-relu in exp domain
                const float wb = fmaxf(pb[0], pb[1]);
                af.u[p] = __builtin_amdgcn_perm(__float_as_uint(wb), __float_as_uint(wa),
                                                0x07060302u) & mm[p];
            }
            #pragma unroll
            for (int nt = 0; nt < 4; ++nt)
                acc[nt] = __builtin_amdgcn_mfma_f32_16x16x32_bf16(af.v, bcur[nt], acc[nt], 0, 0, 0);
            accd = __builtin_amdgcn_mfma_f32_16x16x32_bf16(af.v, bones.v, accd, 0, 0, 0);
        }
    };

    // ---- prologue: chunks 0,1 into reg sets A,B; stage chunk0 -> buf0 ----
    const int KEND = K0 + KR;
    loadPref(K0, ajA, evA0, evA1);
    loadPref(K0 + BJ < KEND ? K0 + BJ : K0, ajB, evB0, evB1);
    stage(0, ajA, evA0, evA1);
    __syncthreads();

    // ---- main loop, 2 chunks per iteration (KR/BJ is even: 1024/128 = 8) ----
    for (int jc = K0; jc < KEND; jc += 2 * BJ) {
        int j2 = jc + 2 * BJ; if (j2 >= KEND) j2 = K0;
        loadPref(j2, ajA, evA0, evA1);          // chunk c+2 -> set A
        computeChunk(0, jc);                     // chunk c from buf0
        stage(1, ajB, evB0, evB1);               // chunk c+1 -> buf1
        __syncthreads();

        int j3 = jc + 3 * BJ; if (j3 >= KEND) j3 = K0;
        loadPref(j3, ajB, evB0, evB1);          // chunk c+3 -> set B
        computeChunk(1, jc + BJ);                // chunk c+1 from buf1
        stage(0, ajA, evA0, evA1);               // chunk c+2 -> buf0
        __syncthreads();
    }

    // ---- epilogue: disjoint per-split writes, no atomics ----
    const size_t sOut = (size_t)blockIdx.y * n * HD;
    #pragma unroll
    for (int nt = 0; nt < 4; ++nt)
        #pragma unroll
        for (int r = 0; r < 4; ++r)
            outsp[sOut + (size_t)(i0 + q * 4 + r) * HD + wave * ODIM + nt * 16 + l16] = acc[nt][r];
    if (l16 == 0) {
        #pragma unroll
        for (int r = 0; r < 4; ++r)
            densp[((size_t)blockIdx.y * n + i0 + q * 4 + r) * HEADS + wave] = accd[r];
    }
}

// ============ normalize: out = sum_s outsp / sum_s densp ============
__global__ __launch_bounds__(256) void normalize(const float* __restrict__ outsp,
                                                 const float* __restrict__ densp,
                                                 float* __restrict__ out, int n, int splits) {
    const int g = blockIdx.x * 256 + threadIdx.x;
    const int i = g >> 6;
    const int c4 = (g & 63) * 4;
    const int head = c4 >> 6;
    float den = 0.f;
    for (int s = 0; s < splits; ++s) den += densp[((size_t)s * n + i) * HEADS + head];
    float4 v = {0.f, 0.f, 0.f, 0.f};
    for (int s = 0; s < splits; ++s) {
        const float4 t = *(const float4*)&outsp[(size_t)s * n * HD + (size_t)i * HD + c4];
        v.x += t.x; v.y += t.y; v.z += t.z; v.w += t.w;
    }
    const float inv = 1.0f / den;
    v.x *= inv; v.y *= inv; v.z *= inv; v.w *= inv;
    *(float4*)&out[(size_t)i * HD + c4] = v;
}

extern "C" void kernel_launch(void* const* d_in, const int* in_sizes, int n_in,
                              void* d_out, int out_size, void* d_ws, size_t ws_size,
                              hipStream_t stream) {
    const float* x   = (const float*)d_in[0];
    const int*   adj = (const int*)d_in[1];
    const float* W   = (const float*)d_in[2];
    const float* att = (const float*)d_in[3];
    float* out = (float*)d_out;

    const int in_dim = in_sizes[2] / HD;   // 256
    const int n = in_sizes[0] / in_dim;    // 4096

    char* ws = (char*)d_ws;
    size_t off = 0;
    auto alloc = [&](size_t bytes) -> void* {
        void* p = ws + off; off += (bytes + 255) & ~(size_t)255; return p;
    };
    __hip_bfloat16* xh = (__hip_bfloat16*)alloc((size_t)n * in_dim * 2);
    __hip_bfloat16* xl = (__hip_bfloat16*)alloc((size_t)n * in_dim * 2);
    __hip_bfloat16* wh = (__hip_bfloat16*)alloc((size_t)in_dim * HD * 2);
    __hip_bfloat16* wl = (__hip_bfloat16*)alloc((size_t)in_dim * HD * 2);
    float4*         E4 = (float4*)alloc((size_t)n * HEADS * 16);
    __hip_bfloat16* hbB = (__hip_bfloat16*)alloc((size_t)n * HD * 2);

    const size_t outB = (size_t)n * HD * 4, denB = (size_t)n * HEADS * 4;
    float* densp = (float*)alloc((size_t)SPLITS * denB);
    float* outsp = (float*)alloc((size_t)SPLITS * outB);

    const int nxb = (n / 16) * (in_dim / 32) * 64 / 256;
    const int nwb = (HD / 16) * (in_dim / 32) * 64 / 256;
    pack_xw<<<nxb + nwb, 256, 0, stream>>>(x, W, xh, xl, wh, wl, in_dim, nxb);
    gemm_fused<<<dim3(n / 32, HEADS), 128, 0, stream>>>(xh, xl, wh, wl, att, E4, hbB, n, in_dim);
    aggregate<<<dim3(n / 16, SPLITS), 256, 0, stream>>>(adj, E4, hbB, outsp, densp, n, n / SPLITS);
    normalize<<<n * 64 / 256, 256, 0, stream>>>(outsp, densp, out, n, SPLITS);
}